// Round 11
// baseline (106.890 us; speedup 1.0000x reference)
//
#include <hip/hip_runtime.h>
#include <hip/hip_cooperative_groups.h>

namespace cg = cooperative_groups;

typedef _Float16 half8   __attribute__((ext_vector_type(8)));
typedef float    floatx4 __attribute__((ext_vector_type(4)));

#define STEP  (6.0f / 63.0f)
#define SCAL  1.69864636f     // sqrt(2*log2(e)):  exp(-2 d^2) = 2^(-(S d)^2)

// Tables in MFMA fragment order (f16) — hot-loop reads are lane-contiguous
// 16B global loads (coalesced, L2/L3-resident).
//   EyF [b][s:32][ct:4][l:64][j:8] : Ey[col=ct*16+(l&15)][k=s*32+(l>>4)*8+j]
//   ExF [b][s:32][r:64][32]        : Ex[row r][k=s*32+0..31]
//   YbF [b][s:32][l:64][j:8]       : Yb^T[ch=l&15][k=s*32+(l>>4)*8+j]
#define EYF_SZ (16 * 65536)
#define EXF_SZ (16 * 65536)
#define YBF_SZ (16 * 16384)
#define NUNITS 294912         // 131072 EyF + 131072 ExF + 32768 YbF half8-units

// ---- single fused cooperative kernel: tables -> grid.sync -> MFMA GEMM ----
// 256 blocks = b(16) x rw(16: 4-row group); 512 thr = 8 waves = 8 kq.
// Phase A: grid-stride build of all table units (validated R9/R10 body).
// Phase B: every wave: same 4 rows, all 64 cols (4 ct), k-eighth; in-block
// k-reduction via 3-round LDS tree; fused normalize + coalesced store.
__global__ __launch_bounds__(512, 2) void rkhs_fused(
    const float* __restrict__ X, const float* __restrict__ Y,
    _Float16* __restrict__ EyF, _Float16* __restrict__ ExF,
    _Float16* __restrict__ YbF, float* __restrict__ out)
{
    __shared__ floatx4 spark[4096];     // 64 KB: 4 slots x 1024 float4
    float* sfin = (float*)spark;        // reused for the final [256 m][9] tile

    const int tid = threadIdx.x;

    // ================= phase A: tables =================
    for (int gid = blockIdx.x * 512 + tid; gid < NUNITS; gid += 131072) {
        if (gid < 131072) {                                 // EyF units
            const int n = gid & 15, q = (gid >> 4) & 3, ct = (gid >> 6) & 3,
                      s = (gid >> 8) & 31, b = gid >> 13;
            const int col = ct * 16 + n, k0 = s * 32 + q * 8;
            const float gS = SCAL * (-3.0f + (float)col * STEP);
            half8 h;
#pragma unroll
            for (int j = 0; j < 8; ++j) {
                const float x = X[(((b << 10) + k0 + j) << 1) + 1];
                const float d = fmaf(-SCAL, x, gS);
                h[j] = (_Float16)__builtin_amdgcn_exp2f(-(d * d));
            }
            *(half8*)(EyF + (size_t)gid * 8) = h;
        } else if (gid < 262144) {                          // ExF units
            const int u = gid - 131072;
            const int qq = u & 3, r = (u >> 2) & 63, s = (u >> 8) & 31, b = u >> 13;
            const int k0 = s * 32 + qq * 8;
            const float gS = SCAL * (-3.0f + (float)r * STEP);
            half8 h;
#pragma unroll
            for (int j = 0; j < 8; ++j) {
                const float x = X[(((b << 10) + k0 + j) << 1)];
                const float d = fmaf(-SCAL, x, gS);
                h[j] = (_Float16)__builtin_amdgcn_exp2f(-(d * d));
            }
            *(half8*)(ExF + (size_t)u * 8) = h;
        } else {                                            // YbF units
            const int v = gid - 262144;
            const int n = v & 15, q = (v >> 4) & 3, s = (v >> 6) & 31, b = v >> 11;
            const int k0 = s * 32 + q * 8;
            half8 h;
#pragma unroll
            for (int j = 0; j < 8; ++j) {
                float val = 0.f;
                if (n == 0)      val = 1.f;
                else if (n <= 8) val = Y[(((b << 10) + k0 + j) << 3) + n - 1];
                h[j] = (_Float16)val;
            }
            *(half8*)(YbF + (size_t)v * 8) = h;
        }
    }

    cg::this_grid().sync();

    // ================= phase B: GEMM =================
    const int b   = blockIdx.x >> 4;
    const int rw  = blockIdx.x & 15;
    const int kq  = tid >> 6, l = tid & 63, q = l >> 4, n = l & 15;
    const int r0  = rw * 4;

    // grid coords output (b==0 blocks, 512 floats each)
    if (b == 0) {
        const int row = r0 + (tid >> 7), rem = tid & 127;
        out[(size_t)rw * 512 + tid] = (rem & 1)
            ? (-3.0f + (float)(rem >> 1) * STEP)
            : (-3.0f + (float)row * STEP);
    }

    floatx4 acc[4][4];                  // [rr][ct]
#pragma unroll
    for (int rr = 0; rr < 4; ++rr)
#pragma unroll
        for (int ct = 0; ct < 4; ++ct) acc[rr][ct] = (floatx4){0.f, 0.f, 0.f, 0.f};

#pragma unroll
    for (int ss = 0; ss < 4; ++ss) {
        const int s = kq * 4 + ss;
        const size_t sb = (size_t)(b * 32 + s);
        const half8 yb = *(const half8*)(YbF + (sb * 64 + l) * 8);
        half8 bp[4];
#pragma unroll
        for (int rr = 0; rr < 4; ++rr) {
            const half8 ex = *(const half8*)(ExF + (sb * 64 + r0 + rr) * 32 + q * 8);
            bp[rr] = ex * yb;           // 4x v_pk_mul_f16
        }
#pragma unroll
        for (int ct = 0; ct < 4; ++ct) {
            const half8 ey = *(const half8*)(EyF + ((sb * 4 + ct) * 64 + l) * 8);
#pragma unroll
            for (int rr = 0; rr < 4; ++rr)
                acc[rr][ct] = __builtin_amdgcn_mfma_f32_16x16x32_f16(ey, bp[rr], acc[rr][ct], 0, 0, 0);
        }
    }

    // ---- 3-round tree reduction over kq (lane-contiguous float4) ----
#define PARKA(slot)                                                        \
    { _Pragma("unroll") for (int rr = 0; rr < 4; ++rr)                     \
      _Pragma("unroll") for (int ct = 0; ct < 4; ++ct)                     \
          spark[(slot) * 1024 + (rr * 4 + ct) * 64 + l] = acc[rr][ct]; }
#define ABSORBA(slot)                                                      \
    { _Pragma("unroll") for (int rr = 0; rr < 4; ++rr)                     \
      _Pragma("unroll") for (int ct = 0; ct < 4; ++ct)                     \
          acc[rr][ct] += spark[(slot) * 1024 + (rr * 4 + ct) * 64 + l]; }

    if (kq >= 4) PARKA(kq - 4)
    __syncthreads();
    if (kq < 4)  ABSORBA(kq)
    __syncthreads();
    if (kq == 2 || kq == 3) PARKA(kq - 2)
    __syncthreads();
    if (kq < 2)  ABSORBA(kq)
    __syncthreads();
    if (kq == 1) PARKA(0)
    __syncthreads();

    if (kq == 0) {
        ABSORBA(0)
        // write the reduced tile into LDS as [m-within-block 256][9]
#pragma unroll
        for (int rr = 0; rr < 4; ++rr)
#pragma unroll
            for (int ct = 0; ct < 4; ++ct)
                if (n < 9)
#pragma unroll
                    for (int i = 0; i < 4; ++i)
                        sfin[(rr * 64 + ct * 16 + q * 4 + i) * 9 + n] = acc[rr][ct][i];
    }
#undef PARKA
#undef ABSORBA
    __syncthreads();

    // ---- fused normalize + coalesced store (2304 contiguous floats) ----
    const size_t obase = 8192 + ((size_t)b * 4096 + (size_t)r0 * 64) * 9;
#pragma unroll
    for (int it = 0; it < 5; ++it) {
        const int idx = it * 512 + tid;
        if (idx < 2304) {
            const int m  = idx / 9;
            const int ch = idx - m * 9;
            const float dens = sfin[m * 9];
            const float v    = sfin[idx];
            out[obase + idx] = ch ? v * __builtin_amdgcn_rcpf(dens + 1e-6f) : dens;
        }
    }
}

extern "C" void kernel_launch(void* const* d_in, const int* in_sizes, int n_in,
                              void* d_out, int out_size, void* d_ws, size_t ws_size,
                              hipStream_t stream) {
    const float* X = (const float*)d_in[0];   // (16,1024,2) fp32
    const float* Y = (const float*)d_in[1];   // (16,1024,8) fp32
    float* out = (float*)d_out;

    _Float16* EyF = (_Float16*)d_ws;
    _Float16* ExF = EyF + EYF_SZ;
    _Float16* YbF = ExF + EXF_SZ;

    void* args[] = {(void*)&X, (void*)&Y, (void*)&EyF, (void*)&ExF,
                    (void*)&YbF, (void*)&out};
    hipLaunchCooperativeKernel((const void*)rkhs_fused, dim3(256), dim3(512),
                               args, 0, stream);
}

// Round 12
// 65.981 us; speedup vs baseline: 1.6200x; 1.6200x over previous
//
#include <hip/hip_runtime.h>

typedef _Float16 half8   __attribute__((ext_vector_type(8)));
typedef float    floatx4 __attribute__((ext_vector_type(4)));

#define STEP  (6.0f / 63.0f)
#define SCAL  1.69864636f     // sqrt(2*log2(e)):  exp(-2 d^2) = 2^(-(S d)^2)

// Single regular launch. 256 blocks = b(16) x rw(16: 4-row group); 512 thr
// = 8 waves. Per 256-k chunk: stage X/Y raw (coalesced), build f16 MFMA
// fragments in LDS (Ey recomputed per block: 8x dup = ~18M exps chip-wide,
// ~0.5us), wave w computes s-slice w (4 ct x 4 rows = 16 MFMA). After 4
// chunks: R10's validated 3-round LDS k-tree + fused normalize + store.
//
// LDS map (bytes in smem[65536]):
//   sX   float2[256]        @     0  (2 KB)   raw X chunk
//   sYf  float [256][8]     @  2048  (8 KB)   raw Y chunk
//   sEx  f16 [8][4][32]     @ 10240  (2 KB)   row frags
//   sYb  f16 [8][64][8]     @ 12288  (8 KB)   Yb^T frags
//   sEy  f16 [8][4][64][8]  @ 20480  (32 KB)  col frags
//   spark floatx4[4096]     @     0  (64 KB)  reduction (after final sync)
__global__ __launch_bounds__(512, 2) void rkhs_fused(
    const float* __restrict__ X,   // (16,1024,2)
    const float* __restrict__ Y,   // (16,1024,8)
    float* __restrict__ out)       // [grid: 8192][Y_grid: 16*4096*9]
{
    __shared__ __align__(16) unsigned char smem[65536];
    float2*   sX    = (float2*)smem;
    float*    sYf   = (float*)(smem + 2048);
    _Float16* sEx   = (_Float16*)(smem + 10240);
    _Float16* sYb   = (_Float16*)(smem + 12288);
    _Float16* sEy   = (_Float16*)(smem + 20480);
    floatx4*  spark = (floatx4*)smem;
    float*    sfin  = (float*)smem;

    const int b   = blockIdx.x >> 4;
    const int rw  = blockIdx.x & 15;
    const int tid = threadIdx.x;
    const int w   = tid >> 6, l = tid & 63, q = l >> 4, n = l & 15;
    const int r0  = rw * 4;

    // grid coords output (b==0 blocks, 512 floats each)
    if (b == 0) {
        const int row = r0 + (tid >> 7), rem = tid & 127;
        out[(size_t)rw * 512 + tid] = (rem & 1)
            ? (-3.0f + (float)(rem >> 1) * STEP)
            : (-3.0f + (float)row * STEP);
    }

    floatx4 acc[4][4];                  // [rr][ct]
#pragma unroll
    for (int rr = 0; rr < 4; ++rr)
#pragma unroll
        for (int ct = 0; ct < 4; ++ct) acc[rr][ct] = (floatx4){0.f, 0.f, 0.f, 0.f};

    for (int c = 0; c < 4; ++c) {
        const int kb = c * 256;
        __syncthreads();                         // prior chunk fully consumed
        // ---- stage raw X/Y chunk (coalesced) ----
        if (tid < 256)
            sX[tid] = ((const float2*)X)[b * 1024 + kb + tid];
        ((float4*)sYf)[tid] =
            ((const float4*)(Y + ((size_t)b * 1024 + kb) * 8))[tid];
        __syncthreads();

        // ---- build fragments in LDS ----
        if (tid < 128) {                         // sEx: (s_loc, rr, q) units
            const int s_loc = tid >> 4, rr = (tid >> 2) & 3, qq = tid & 3;
            const int kk = s_loc * 32 + qq * 8;
            const float gS = SCAL * (-3.0f + (float)(r0 + rr) * STEP);
            half8 h;
#pragma unroll
            for (int j = 0; j < 8; ++j) {
                const float d = fmaf(-SCAL, sX[kk + j].x, gS);
                h[j] = (_Float16)__builtin_amdgcn_exp2f(-(d * d));
            }
            *(half8*)(sEx + (s_loc * 4 + rr) * 32 + qq * 8) = h;
        }
        {                                        // sYb: (s_loc, l) units
            const int kk = w * 32 + q * 8;       // s_loc == w
            half8 h;
#pragma unroll
            for (int j = 0; j < 8; ++j) {
                float v = 0.f;
                if (n == 0)      v = 1.f;
                else if (n <= 8) v = sYf[(kk + j) * 8 + n - 1];
                h[j] = (_Float16)v;
            }
            *(half8*)(sYb + (w * 64 + l) * 8) = h;
        }
#pragma unroll
        for (int i = 0; i < 4; ++i) {            // sEy: 4 units/thread
            const int u = tid + 512 * i;         // [s_loc][ct][l] linear
            const int ll = u & 63;
            const int kk = ((u >> 8) & 7) * 32 + (ll >> 4) * 8;
            const int col = ((u >> 6) & 3) * 16 + (ll & 15);
            const float gS = SCAL * (-3.0f + (float)col * STEP);
            half8 h;
#pragma unroll
            for (int j = 0; j < 8; ++j) {
                const float d = fmaf(-SCAL, sX[kk + j].y, gS);
                h[j] = (_Float16)__builtin_amdgcn_exp2f(-(d * d));
            }
            *(half8*)(sEy + (size_t)u * 8) = h;
        }
        __syncthreads();

        // ---- compute: wave w consumes s-slice w ----
        {
            const half8 yb = *(const half8*)(sYb + (w * 64 + l) * 8);
            half8 bp[4];
#pragma unroll
            for (int rr = 0; rr < 4; ++rr)
                bp[rr] = (*(const half8*)(sEx + (w * 4 + rr) * 32 + q * 8)) * yb;
#pragma unroll
            for (int ct = 0; ct < 4; ++ct) {
                const half8 ey = *(const half8*)(sEy + ((w * 4 + ct) * 64 + l) * 8);
#pragma unroll
                for (int rr = 0; rr < 4; ++rr)
                    acc[rr][ct] = __builtin_amdgcn_mfma_f32_16x16x32_f16(ey, bp[rr], acc[rr][ct], 0, 0, 0);
            }
        }
    }
    __syncthreads();                 // all compute done; LDS free for spark

    // ---- 3-round tree reduction over waves (lane-contiguous float4) ----
#define PARKA(slot)                                                        \
    { _Pragma("unroll") for (int rr = 0; rr < 4; ++rr)                     \
      _Pragma("unroll") for (int ct = 0; ct < 4; ++ct)                     \
          spark[(slot) * 1024 + (rr * 4 + ct) * 64 + l] = acc[rr][ct]; }
#define ABSORBA(slot)                                                      \
    { _Pragma("unroll") for (int rr = 0; rr < 4; ++rr)                     \
      _Pragma("unroll") for (int ct = 0; ct < 4; ++ct)                     \
          acc[rr][ct] += spark[(slot) * 1024 + (rr * 4 + ct) * 64 + l]; }

    if (w >= 4) PARKA(w - 4)
    __syncthreads();
    if (w < 4)  ABSORBA(w)
    __syncthreads();
    if (w == 2 || w == 3) PARKA(w - 2)
    __syncthreads();
    if (w < 2)  ABSORBA(w)
    __syncthreads();
    if (w == 1) PARKA(0)
    __syncthreads();

    if (w == 0) {
        ABSORBA(0)
        // reduced tile into LDS as [m-within-block 256][9]
#pragma unroll
        for (int rr = 0; rr < 4; ++rr)
#pragma unroll
            for (int ct = 0; ct < 4; ++ct)
                if (n < 9)
#pragma unroll
                    for (int i = 0; i < 4; ++i)
                        sfin[(rr * 64 + ct * 16 + q * 4 + i) * 9 + n] = acc[rr][ct][i];
    }
#undef PARKA
#undef ABSORBA
    __syncthreads();

    // ---- fused normalize + coalesced store (2304 contiguous floats) ----
    const size_t obase = 8192 + ((size_t)b * 4096 + (size_t)r0 * 64) * 9;
#pragma unroll
    for (int it = 0; it < 5; ++it) {
        const int idx = it * 512 + tid;
        if (idx < 2304) {
            const int m  = idx / 9;
            const int ch = idx - m * 9;
            const float dens = sfin[m * 9];
            const float v    = sfin[idx];
            out[obase + idx] = ch ? v * __builtin_amdgcn_rcpf(dens + 1e-6f) : dens;
        }
    }
}

extern "C" void kernel_launch(void* const* d_in, const int* in_sizes, int n_in,
                              void* d_out, int out_size, void* d_ws, size_t ws_size,
                              hipStream_t stream) {
    const float* X = (const float*)d_in[0];   // (16,1024,2) fp32
    const float* Y = (const float*)d_in[1];   // (16,1024,8) fp32
    float* out = (float*)d_out;

    rkhs_fused<<<dim3(256), dim3(512), 0, stream>>>(X, Y, out);
}

// Round 13
// 62.700 us; speedup vs baseline: 1.7048x; 1.0523x over previous
//
#include <hip/hip_runtime.h>

typedef _Float16 half8   __attribute__((ext_vector_type(8)));
typedef float    floatx4 __attribute__((ext_vector_type(4)));

#define STEP  (6.0f / 63.0f)
#define SCAL  1.69864636f     // sqrt(2*log2(e)):  exp(-2 d^2) = 2^(-(S d)^2)

// Single launch, 256 blocks = b(16) x rw(16: 4-row group); 512 thr = 8 waves.
// Wave w: rows rw*4..+3, all 64 cols (4 ct-tiles), k in [w*128, w*128+128).
// Barrier-free main loop: A-frag (ey) built in registers per lane (the exp
// work is lane-parallel in MFMA fragment layout), yb register-resident for
// the whole kernel, ex + S*Xy from two tiny LDS tables built once at start.
// Then R12's validated 3-round LDS k-tree + fused normalize + store.
__global__ __launch_bounds__(512, 2) void rkhs_fused(
    const float* __restrict__ X,   // (16,1024,2)
    const float* __restrict__ Y,   // (16,1024,8)
    float* __restrict__ out)       // [grid: 8192][Y_grid: 16*4096*9]
{
    __shared__ __align__(16) unsigned char smem[65536];
    float*    sXy   = (float*)smem;              // [1024] S*X.y   (4 KB)
    _Float16* sEx   = (_Float16*)(smem + 4096);  // [32 s][4 r][32 k] (8 KB)
    floatx4*  spark = (floatx4*)smem;            // reduction alias (64 KB)
    float*    sfin  = (float*)smem;              // final tile alias

    const int b   = blockIdx.x >> 4;
    const int rw  = blockIdx.x & 15;
    const int tid = threadIdx.x;
    const int w   = tid >> 6, l = tid & 63, q = l >> 4, n = l & 15;
    const int r0  = rw * 4;

    // ---- phase 0a: S*X.y table (all 512 threads, 2 vals each) ----
    {
        const float2 v0 = ((const float2*)X)[b * 1024 + 2 * tid];
        const float2 v1 = ((const float2*)X)[b * 1024 + 2 * tid + 1];
        sXy[2 * tid]     = SCAL * v0.y;
        sXy[2 * tid + 1] = SCAL * v1.y;
    }

    // grid coords output (b==0 blocks, 512 floats each) — validated R12
    if (b == 0) {
        const int row = r0 + (tid >> 7), rem = tid & 127;
        out[(size_t)rw * 512 + tid] = (rem & 1)
            ? (-3.0f + (float)(rem >> 1) * STEP)
            : (-3.0f + (float)row * STEP);
    }

    // ---- phase 0b: yb register-resident (32 f16/lane, loaded once) ----
    // ybr[ss][j] = Yb[ch=n][k = (w*4+ss)*32 + q*8 + j]
    half8 ybr[4];
#pragma unroll
    for (int ss = 0; ss < 4; ++ss) {
        half8 h;
        if (n == 0) {
#pragma unroll
            for (int j = 0; j < 8; ++j) h[j] = (_Float16)1.0f;
        } else if (n <= 8) {
            const float* yp = Y + ((size_t)(b * 1024 + (w * 4 + ss) * 32 + q * 8)) * 8 + (n - 1);
#pragma unroll
            for (int j = 0; j < 8; ++j) h[j] = (_Float16)yp[j * 8];
        } else {
#pragma unroll
            for (int j = 0; j < 8; ++j) h[j] = (_Float16)0.0f;
        }
        ybr[ss] = h;
    }

    // ---- phase 0c: sEx table (128 threads x 32 exps) ----
    if (tid < 128) {
        const int s = tid >> 2, rr = tid & 3;
        const float gS = SCAL * (-3.0f + (float)(r0 + rr) * STEP);
        const float* xp = X + (size_t)(b * 1024 + s * 32) * 2;
#pragma unroll
        for (int g = 0; g < 4; ++g) {
            half8 hbuf;
#pragma unroll
            for (int j = 0; j < 8; ++j) {
                const float d = fmaf(-SCAL, xp[(g * 8 + j) * 2], gS);
                hbuf[j] = (_Float16)__builtin_amdgcn_exp2f(-(d * d));
            }
            *(half8*)(sEx + (s * 4 + rr) * 32 + g * 8) = hbuf;
        }
    }
    __syncthreads();                 // the only barrier before the tree

    float gSct[4];
#pragma unroll
    for (int ct = 0; ct < 4; ++ct)
        gSct[ct] = SCAL * (-3.0f + (float)(ct * 16 + n) * STEP);

    floatx4 acc[4][4];               // [rr][ct]
#pragma unroll
    for (int rr = 0; rr < 4; ++rr)
#pragma unroll
        for (int ct = 0; ct < 4; ++ct) acc[rr][ct] = (floatx4){0.f, 0.f, 0.f, 0.f};

    // ---- main loop: 4 s-steps, no barriers, no staging ----
#pragma unroll
    for (int ss = 0; ss < 4; ++ss) {
        const int s   = w * 4 + ss;
        const int k0q = s * 32 + q * 8;
        const float4 xa = *(const float4*)(sXy + k0q);        // broadcast b128
        const float4 xb = *(const float4*)(sXy + k0q + 4);
        const float xk[8] = {xa.x, xa.y, xa.z, xa.w, xb.x, xb.y, xb.z, xb.w};

        half8 bp[4];
#pragma unroll
        for (int rr = 0; rr < 4; ++rr)
            bp[rr] = (*(const half8*)(sEx + (s * 4 + rr) * 32 + q * 8)) * ybr[ss];

#pragma unroll
        for (int ct = 0; ct < 4; ++ct) {
            half8 ey;                                   // A-frag in registers
#pragma unroll
            for (int j = 0; j < 8; ++j) {
                const float d = gSct[ct] - xk[j];
                ey[j] = (_Float16)__builtin_amdgcn_exp2f(-(d * d));
            }
#pragma unroll
            for (int rr = 0; rr < 4; ++rr)
                acc[rr][ct] = __builtin_amdgcn_mfma_f32_16x16x32_f16(ey, bp[rr], acc[rr][ct], 0, 0, 0);
        }
    }
    __syncthreads();                 // compute done; LDS free for spark

    // ---- 3-round tree reduction over waves (validated R12) ----
#define PARKA(slot)                                                        \
    { _Pragma("unroll") for (int rr = 0; rr < 4; ++rr)                     \
      _Pragma("unroll") for (int ct = 0; ct < 4; ++ct)                     \
          spark[(slot) * 1024 + (rr * 4 + ct) * 64 + l] = acc[rr][ct]; }
#define ABSORBA(slot)                                                      \
    { _Pragma("unroll") for (int rr = 0; rr < 4; ++rr)                     \
      _Pragma("unroll") for (int ct = 0; ct < 4; ++ct)                     \
          acc[rr][ct] += spark[(slot) * 1024 + (rr * 4 + ct) * 64 + l]; }

    if (w >= 4) PARKA(w - 4)
    __syncthreads();
    if (w < 4)  ABSORBA(w)
    __syncthreads();
    if (w == 2 || w == 3) PARKA(w - 2)
    __syncthreads();
    if (w < 2)  ABSORBA(w)
    __syncthreads();
    if (w == 1) PARKA(0)
    __syncthreads();

    if (w == 0) {
        ABSORBA(0)
        // reduced tile into LDS as [m-within-block 256][9]
#pragma unroll
        for (int rr = 0; rr < 4; ++rr)
#pragma unroll
            for (int ct = 0; ct < 4; ++ct)
                if (n < 9)
#pragma unroll
                    for (int i = 0; i < 4; ++i)
                        sfin[(rr * 64 + ct * 16 + q * 4 + i) * 9 + n] = acc[rr][ct][i];
    }
#undef PARKA
#undef ABSORBA
    __syncthreads();

    // ---- fused normalize + coalesced store (2304 contiguous floats) ----
    const size_t obase = 8192 + ((size_t)b * 4096 + (size_t)r0 * 64) * 9;
#pragma unroll
    for (int it = 0; it < 5; ++it) {
        const int idx = it * 512 + tid;
        if (idx < 2304) {
            const int m  = idx / 9;
            const int ch = idx - m * 9;
            const float dens = sfin[m * 9];
            const float v    = sfin[idx];
            out[obase + idx] = ch ? v * __builtin_amdgcn_rcpf(dens + 1e-6f) : dens;
        }
    }
}

extern "C" void kernel_launch(void* const* d_in, const int* in_sizes, int n_in,
                              void* d_out, int out_size, void* d_ws, size_t ws_size,
                              hipStream_t stream) {
    const float* X = (const float*)d_in[0];   // (16,1024,2) fp32
    const float* Y = (const float*)d_in[1];   // (16,1024,8) fp32
    float* out = (float*)d_out;
    (void)d_ws; (void)ws_size;

    rkhs_fused<<<dim3(256), dim3(512), 0, stream>>>(X, Y, out);
}

// Round 15
// 62.182 us; speedup vs baseline: 1.7190x; 1.0083x over previous
//
#include <hip/hip_runtime.h>

typedef _Float16 half8 __attribute__((ext_vector_type(8)));
typedef __fp16   h2 __attribute__((ext_vector_type(2)));
typedef __fp16   h4 __attribute__((ext_vector_type(4)));
typedef __fp16   h8 __attribute__((ext_vector_type(8)));
typedef float    floatx4 __attribute__((ext_vector_type(4)));
typedef float    fv2 __attribute__((ext_vector_type(2)));
typedef float    fv4 __attribute__((ext_vector_type(4)));

#define STEP  (6.0f / 63.0f)
#define SCAL  1.69864636f     // sqrt(2*log2(e)):  exp(-2 d^2) = 2^(-(S d)^2)

// Single launch, 256 blocks = b(16) x rw(16: 4-row group); 512 thr = 8 waves.
// Wave w: rows rw*4..+3, all 64 cols (4 ct-tiles), k in [w*128, w*128+128).
// R13 structure with: (a) one cold b128 X read/thread -> S*Xx,S*Xy in LDS,
// sEx built by all 512 threads from LDS (no duplicate cold global round);
// (b) ybr gathers hoisted to kernel start (all cold misses concurrent);
// (c) packed fv2 math + v_cvt_pkrtz in the ey chain.
__global__ __launch_bounds__(512, 2) void rkhs_fused(
    const float* __restrict__ X,   // (16,1024,2)
    const float* __restrict__ Y,   // (16,1024,8)
    float* __restrict__ out)       // [grid: 8192][Y_grid: 16*4096*9]
{
    __shared__ __align__(16) unsigned char smem[65536];
    float*    sXx   = (float*)smem;              // [1024] S*X.x   (4 KB)
    float*    sXy   = (float*)(smem + 4096);     // [1024] S*X.y   (4 KB)
    _Float16* sEx   = (_Float16*)(smem + 8192);  // [32 s][4 r][32 k] (8 KB)
    floatx4*  spark = (floatx4*)smem;            // reduction alias (64 KB)
    float*    sfin  = (float*)smem;              // final tile alias

    const int b   = blockIdx.x >> 4;
    const int rw  = blockIdx.x & 15;
    const int tid = threadIdx.x;
    const int w   = tid >> 6, l = tid & 63, q = l >> 4, n = l & 15;
    const int r0  = rw * 4;

    // ---- issue ALL cold global loads up front (concurrent misses) ----
    const fv4 xv = *(const fv4*)(X + (size_t)b * 2048 + tid * 4); // X[b][2tid..+1]

    float ybf[4][8];
    const bool ldy = (n >= 1 && n <= 8);
    if (ldy) {
#pragma unroll
        for (int ss = 0; ss < 4; ++ss) {
            const float* yp = Y + ((size_t)(b * 1024 + (w * 4 + ss) * 32 + q * 8)) * 8 + (n - 1);
#pragma unroll
            for (int j = 0; j < 8; ++j) ybf[ss][j] = yp[j * 8];
        }
    }

    // grid coords output (b==0 blocks, 512 floats each)
    if (b == 0) {
        const int row = r0 + (tid >> 7), rem = tid & 127;
        out[(size_t)rw * 512 + tid] = (rem & 1)
            ? (-3.0f + (float)(rem >> 1) * STEP)
            : (-3.0f + (float)row * STEP);
    }

    // ---- stage S*X into LDS ----
    sXx[2 * tid]     = SCAL * xv[0];
    sXy[2 * tid]     = SCAL * xv[1];
    sXx[2 * tid + 1] = SCAL * xv[2];
    sXy[2 * tid + 1] = SCAL * xv[3];
    __syncthreads();

    // ---- sEx: all 512 threads, 8 exps each, inputs from LDS ----
    {
        const int s = tid >> 4, rr = (tid >> 2) & 3, g = tid & 3;
        const float gS = SCAL * (-3.0f + (float)(r0 + rr) * STEP);
        const float* xp = sXx + s * 32 + g * 8;
        h2 p[4];
#pragma unroll
        for (int hh = 0; hh < 4; ++hh) {
            const float d0 = gS - xp[2 * hh];
            const float d1 = gS - xp[2 * hh + 1];
            p[hh] = __builtin_amdgcn_cvt_pkrtz(
                __builtin_amdgcn_exp2f(-(d0 * d0)),
                __builtin_amdgcn_exp2f(-(d1 * d1)));
        }
        const h8 packed = __builtin_shufflevector(
            __builtin_shufflevector(p[0], p[1], 0, 1, 2, 3),
            __builtin_shufflevector(p[2], p[3], 0, 1, 2, 3),
            0, 1, 2, 3, 4, 5, 6, 7);
        *(half8*)(sEx + (s * 4 + rr) * 32 + g * 8) = __builtin_bit_cast(half8, packed);
    }

    // ---- ybr: register-resident B weights (cvt from hoisted gathers) ----
    half8 ybr[4];
#pragma unroll
    for (int ss = 0; ss < 4; ++ss) {
        half8 h;
        if (n == 0) {
#pragma unroll
            for (int j = 0; j < 8; ++j) h[j] = (_Float16)1.0f;
        } else if (ldy) {
#pragma unroll
            for (int j = 0; j < 8; ++j) h[j] = (_Float16)ybf[ss][j];
        } else {
#pragma unroll
            for (int j = 0; j < 8; ++j) h[j] = (_Float16)0.0f;
        }
        ybr[ss] = h;
    }
    __syncthreads();

    float gSct[4];
#pragma unroll
    for (int ct = 0; ct < 4; ++ct)
        gSct[ct] = SCAL * (-3.0f + (float)(ct * 16 + n) * STEP);

    floatx4 acc[4][4];               // [rr][ct]
#pragma unroll
    for (int rr = 0; rr < 4; ++rr)
#pragma unroll
        for (int ct = 0; ct < 4; ++ct) acc[rr][ct] = (floatx4){0.f, 0.f, 0.f, 0.f};

    // ---- main loop: 4 s-steps, no barriers, no staging ----
#pragma unroll
    for (int ss = 0; ss < 4; ++ss) {
        const int s   = w * 4 + ss;
        const int k0q = s * 32 + q * 8;
        const fv4 xa = *(const fv4*)(sXy + k0q);          // broadcast b128
        const fv4 xb = *(const fv4*)(sXy + k0q + 4);
        fv2 xk2[4];
        xk2[0] = __builtin_shufflevector(xa, xa, 0, 1);
        xk2[1] = __builtin_shufflevector(xa, xa, 2, 3);
        xk2[2] = __builtin_shufflevector(xb, xb, 0, 1);
        xk2[3] = __builtin_shufflevector(xb, xb, 2, 3);

        half8 bp[4];
#pragma unroll
        for (int rr = 0; rr < 4; ++rr)
            bp[rr] = (*(const half8*)(sEx + (s * 4 + rr) * 32 + q * 8)) * ybr[ss];

#pragma unroll
        for (int ct = 0; ct < 4; ++ct) {
            const fv2 gS2 = {gSct[ct], gSct[ct]};
            h2 p[4];
#pragma unroll
            for (int hh = 0; hh < 4; ++hh) {
                const fv2 d  = gS2 - xk2[hh];             // v_pk_add_f32
                const fv2 dd = d * d;                     // v_pk_mul_f32
                p[hh] = __builtin_amdgcn_cvt_pkrtz(
                    __builtin_amdgcn_exp2f(-dd[0]),
                    __builtin_amdgcn_exp2f(-dd[1]));
            }
            const h8 packed = __builtin_shufflevector(
                __builtin_shufflevector(p[0], p[1], 0, 1, 2, 3),
                __builtin_shufflevector(p[2], p[3], 0, 1, 2, 3),
                0, 1, 2, 3, 4, 5, 6, 7);
            const half8 ey = __builtin_bit_cast(half8, packed);
#pragma unroll
            for (int rr = 0; rr < 4; ++rr)
                acc[rr][ct] = __builtin_amdgcn_mfma_f32_16x16x32_f16(ey, bp[rr], acc[rr][ct], 0, 0, 0);
        }
    }
    __syncthreads();                 // compute done; LDS free for spark

    // ---- 3-round tree reduction over waves (validated R12/R13) ----
#define PARKA(slot)                                                        \
    { _Pragma("unroll") for (int rr = 0; rr < 4; ++rr)                     \
      _Pragma("unroll") for (int ct = 0; ct < 4; ++ct)                     \
          spark[(slot) * 1024 + (rr * 4 + ct) * 64 + l] = acc[rr][ct]; }
#define ABSORBA(slot)                                                      \
    { _Pragma("unroll") for (int rr = 0; rr < 4; ++rr)                     \
      _Pragma("unroll") for (int ct = 0; ct < 4; ++ct)                     \
          acc[rr][ct] += spark[(slot) * 1024 + (rr * 4 + ct) * 64 + l]; }

    if (w >= 4) PARKA(w - 4)
    __syncthreads();
    if (w < 4)  ABSORBA(w)
    __syncthreads();
    if (w == 2 || w == 3) PARKA(w - 2)
    __syncthreads();
    if (w < 2)  ABSORBA(w)
    __syncthreads();
    if (w == 1) PARKA(0)
    __syncthreads();

    if (w == 0) {
        ABSORBA(0)
        // reduced tile into LDS as [m-within-block 256][9]
#pragma unroll
        for (int rr = 0; rr < 4; ++rr)
#pragma unroll
            for (int ct = 0; ct < 4; ++ct)
                if (n < 9)
#pragma unroll
                    for (int i = 0; i < 4; ++i)
                        sfin[(rr * 64 + ct * 16 + q * 4 + i) * 9 + n] = acc[rr][ct][i];
    }
#undef PARKA
#undef ABSORBA
    __syncthreads();

    // ---- fused normalize + coalesced store (2304 contiguous floats) ----
    const size_t obase = 8192 + ((size_t)b * 4096 + (size_t)r0 * 64) * 9;
#pragma unroll
    for (int it = 0; it < 5; ++it) {
        const int idx = it * 512 + tid;
        if (idx < 2304) {
            const int m  = idx / 9;
            const int ch = idx - m * 9;
            const float dens = sfin[m * 9];
            const float v    = sfin[idx];
            out[obase + idx] = ch ? v * __builtin_amdgcn_rcpf(dens + 1e-6f) : dens;
        }
    }
}

extern "C" void kernel_launch(void* const* d_in, const int* in_sizes, int n_in,
                              void* d_out, int out_size, void* d_ws, size_t ws_size,
                              hipStream_t stream) {
    const float* X = (const float*)d_in[0];   // (16,1024,2) fp32
    const float* Y = (const float*)d_in[1];   // (16,1024,8) fp32
    float* out = (float*)d_out;
    (void)d_ws; (void)ws_size;

    rkhs_fused<<<dim3(256), dim3(512), 0, stream>>>(X, Y, out);
}